// Round 13
// baseline (620.392 us; speedup 1.0000x reference)
//
#include <hip/hip_runtime.h>
#include <hip/hip_bf16.h>

// Problem constants
#define B_ 256
#define T_ 96
#define F_ 368
#define H_ 368
#define G3_ 1104          // 3*H
#define NC_ 29            // fine classes
#define BT_ (B_*T_)       // 24576
#define HB_ (H_*B_)       // 94208, one time-slice of h2 [bg][u][r]

// GRU geometry (v17 structure: v13 bg-major + own-slice bypass + xprojT)
#define NSL 8             // unit slices
#define NU 46             // units per slice (8*46 = 368)
#define NCOL 138          // cols per slice = 3*NU
#define ROWS 8            // batch rows per group
#define WQCOLS 1152       // legacy, overlay sizing

// Wq2 frag store: [us 8][nt 9][kt 12][plane 2][lane 64][e 8] u16 = 1,769,472 B
#define WQ2_U16 (8*9*12*2*64*8)

// h-word sentinel: hi half 0x7FC0 = bf16 NaN; finite h can never produce it,
// so a non-sentinel full-word read proves the producer's store landed.
#define SENT 0x7FC07FC0u

typedef __attribute__((ext_vector_type(8))) short bhalf8;   // 8 bf16 = 4 VGPR
typedef __attribute__((ext_vector_type(4))) float f32x4;

// ---- bf16 split helpers (bit-level RNE, no header dependence) -------------
__device__ __forceinline__ unsigned short f2bf(float x) {
    unsigned u = __float_as_uint(x);
    u += 0x7fffu + ((u >> 16) & 1u);
    return (unsigned short)(u >> 16);
}
__device__ __forceinline__ float bf2f(unsigned short b) {
    return __uint_as_float(((unsigned)b) << 16);
}

// async global->LDS, 16B per lane; lds base must be wave-uniform
__device__ __forceinline__ void gll16(const void* g, void* l) {
    __builtin_amdgcn_global_load_lds(
        (const __attribute__((address_space(1))) void*)g,
        (__attribute__((address_space(3))) void*)l, 16, 0, 0);
}

// ---- fence-free cross-XCD exchange primitives ----------------------------
__device__ __forceinline__ void bstore_u(unsigned int* p, unsigned int v) {
    __hip_atomic_store(p, v, __ATOMIC_RELAXED, __HIP_MEMORY_SCOPE_AGENT);
}
__device__ __forceinline__ unsigned long long bload_u2(const unsigned long long* p) {
    return __hip_atomic_load(p, __ATOMIC_RELAXED, __HIP_MEMORY_SCOPE_AGENT);
}

// LDS-only barrier: orders ds ops across the WG WITHOUT draining vmcnt, so
// in-flight agent-scope h stores keep flying across step boundaries.
__device__ __forceinline__ void barrier_lds() {
    asm volatile("s_waitcnt lgkmcnt(0)\ns_barrier" ::: "memory");
}

// ---------------------------------------------------------------------------
// K0a: FUSED split: blocks [0,8832) split features quads into Ah/Al;
// blocks [8832,10488) split Wi into Bh/Bl (zero-padded to 1152 rows).
// Independent work, one launch, concurrent occupancy.
// ---------------------------------------------------------------------------
__global__ __launch_bounds__(256) void k_split_ab(const float* __restrict__ feat,
                                                  const float* __restrict__ Wi,
                                                  unsigned short* __restrict__ Ah,
                                                  unsigned short* __restrict__ Al,
                                                  unsigned short* __restrict__ Bh,
                                                  unsigned short* __restrict__ Bl) {
    const int bx = blockIdx.x;
    if (bx < 8832) {
        const int idx = bx*256 + threadIdx.x;
        const float4 v = reinterpret_cast<const float4*>(feat)[idx];
        ushort4 h, lo;
        h.x = f2bf(v.x); lo.x = f2bf(v.x - bf2f(h.x));
        h.y = f2bf(v.y); lo.y = f2bf(v.y - bf2f(h.y));
        h.z = f2bf(v.z); lo.z = f2bf(v.z - bf2f(h.z));
        h.w = f2bf(v.w); lo.w = f2bf(v.w - bf2f(h.w));
        reinterpret_cast<ushort4*>(Ah)[idx] = h;
        reinterpret_cast<ushort4*>(Al)[idx] = lo;
    } else {
        const int idx = (bx - 8832)*256 + threadIdx.x;   // < 423936 = 1152*368
        const float x = (idx < G3_*F_) ? Wi[idx] : 0.f;
        const unsigned short h = f2bf(x);
        Bh[idx] = h;
        Bl[idx] = f2bf(x - bf2f(h));
    }
}

// ---------------------------------------------------------------------------
// K0b: FUSED post-xproj prep: blocks [0,432) pack Wh into Wq2 fragments
// (v13 layout); blocks [432,9264) fill h2 with the sentinel (re-poison).
// Both overlays are dead after k_xproj_mfma (stream-ordered).
// ---------------------------------------------------------------------------
__global__ __launch_bounds__(256) void k_prep_fill(const float* __restrict__ Wh,
                                                   unsigned short* __restrict__ Wq2,
                                                   unsigned int* __restrict__ sent) {
    const int bx = blockIdx.x;
    if (bx < 432) {
        const int idx = bx*256 + threadIdx.x;   // < 110592
        const int l = idx & 63;
        const int p = (idx >> 6) & 1;
        int q = idx >> 7;
        const int kt = q % 12; q /= 12;
        const int nt = q % 9;
        const int us = q / 9;
        const int col = nt*16 + (l & 15);
        const int k0 = kt*32 + (l >> 4)*8;
        float v[8];
        #pragma unroll
        for (int e = 0; e < 8; ++e) v[e] = 0.f;
        if (col < NCOL && k0 < H_) {
            const int g = col / NU, uu = col - g*NU;
            const int grow = g*H_ + us*NU + uu;
            const float4 f0 = *reinterpret_cast<const float4*>(Wh + (size_t)grow*H_ + k0);
            const float4 f1 = *reinterpret_cast<const float4*>(Wh + (size_t)grow*H_ + k0 + 4);
            v[0]=f0.x; v[1]=f0.y; v[2]=f0.z; v[3]=f0.w;
            v[4]=f1.x; v[5]=f1.y; v[6]=f1.z; v[7]=f1.w;
        }
        unsigned int o[4];
        #pragma unroll
        for (int e = 0; e < 4; ++e) {
            const unsigned short h0 = f2bf(v[2*e]), h1 = f2bf(v[2*e+1]);
            const unsigned short w0 = p ? f2bf(v[2*e]   - bf2f(h0)) : h0;
            const unsigned short w1 = p ? f2bf(v[2*e+1] - bf2f(h1)) : h1;
            o[e] = (unsigned)w0 | ((unsigned)w1 << 16);
        }
        uint4* dst = reinterpret_cast<uint4*>(Wq2 + (size_t)idx*8);
        *dst = make_uint4(o[0], o[1], o[2], o[3]);
    } else {
        const int idx = (bx - 432)*256 + threadIdx.x;   // < 2260992 uint4
        reinterpret_cast<uint4*>(sent)[idx] = make_uint4(SENT, SENT, SENT, SENT);
    }
}

// ---------------------------------------------------------------------------
// K1: xproj GEMM via split-bf16 MFMA; TRANSPOSED epilogue stores
// xprojT[t][b][g3] (proven rounds 8/10/11/12).
// ---------------------------------------------------------------------------
__global__ __launch_bounds__(256) void k_xproj_mfma(
        const unsigned short* __restrict__ Ah, const unsigned short* __restrict__ Al,
        const unsigned short* __restrict__ Bh, const unsigned short* __restrict__ Bl,
        const float* __restrict__ bias, float* __restrict__ C)
{
    __shared__ unsigned short sAh[128*32], sAl[128*32], sBh[128*32], sBl[128*32];
    const int tid = threadIdx.x;
    const int w   = tid >> 6, l = tid & 63;
    const int gm0 = blockIdx.y * 128, gn0 = blockIdx.x * 128;

    const int srow = tid >> 2;                       // 0..63
    const int cg   = (tid & 3) ^ ((tid >> 3) & 3);   // source k-chunk (0..3)
    const size_t aoff0 = (size_t)(gm0 + srow)      * F_ + cg * 8;
    const size_t aoff1 = (size_t)(gm0 + srow + 64) * F_ + cg * 8;
    const size_t boff0 = (size_t)(gn0 + srow)      * F_ + cg * 8;
    const size_t boff1 = (size_t)(gn0 + srow + 64) * F_ + cg * 8;
    const int lb0 = w * 1024, lb1 = 4096 + w * 1024; // wave-uniform LDS bases

    const int lr = l & 15, lk = l >> 4;
    const int cswz = (lk ^ ((lr >> 1) & 3)) * 16;
    const int wr = w >> 1, wc = w & 1;
    int offA[4], offB[4];
    #pragma unroll
    for (int f = 0; f < 4; ++f) {
        offA[f] = (wr*64 + f*16 + lr) * 64 + cswz;
        offB[f] = (wc*64 + f*16 + lr) * 64 + cswz;
    }

    f32x4 acc[4][4];
    #pragma unroll
    for (int i = 0; i < 4; ++i)
        #pragma unroll
        for (int j = 0; j < 4; ++j) acc[i][j] = f32x4{0.f,0.f,0.f,0.f};

    auto stage = [&](int kt) {
        const size_t ko = (size_t)kt * 32;
        gll16(Ah + aoff0 + ko, (char*)sAh + lb0);
        gll16(Ah + aoff1 + ko, (char*)sAh + lb1);
        gll16(Al + aoff0 + ko, (char*)sAl + lb0);
        gll16(Al + aoff1 + ko, (char*)sAl + lb1);
        gll16(Bh + boff0 + ko, (char*)sBh + lb0);
        gll16(Bh + boff1 + ko, (char*)sBh + lb1);
        gll16(Bl + boff0 + ko, (char*)sBl + lb0);
        gll16(Bl + boff1 + ko, (char*)sBl + lb1);
    };

    stage(0);
    for (int kt = 0; kt < 12; ++kt) {
        __syncthreads();
        if (kt == 11) {
            if (cg >= 2) {
                const f32x4 z = f32x4{0.f,0.f,0.f,0.f};
                *reinterpret_cast<f32x4*>((char*)sAh + tid*16)        = z;
                *reinterpret_cast<f32x4*>((char*)sAh + tid*16 + 4096) = z;
                *reinterpret_cast<f32x4*>((char*)sAl + tid*16)        = z;
                *reinterpret_cast<f32x4*>((char*)sAl + tid*16 + 4096) = z;
                *reinterpret_cast<f32x4*>((char*)sBh + tid*16)        = z;
                *reinterpret_cast<f32x4*>((char*)sBh + tid*16 + 4096) = z;
                *reinterpret_cast<f32x4*>((char*)sBl + tid*16)        = z;
                *reinterpret_cast<f32x4*>((char*)sBl + tid*16 + 4096) = z;
            }
            __syncthreads();
        }
        bhalf8 fAh[4], fAl[4], fBh[4], fBl[4];
        #pragma unroll
        for (int f = 0; f < 4; ++f) {
            fAh[f] = *reinterpret_cast<const bhalf8*>((const char*)sAh + offA[f]);
            fAl[f] = *reinterpret_cast<const bhalf8*>((const char*)sAl + offA[f]);
            fBh[f] = *reinterpret_cast<const bhalf8*>((const char*)sBh + offB[f]);
            fBl[f] = *reinterpret_cast<const bhalf8*>((const char*)sBl + offB[f]);
        }
        __syncthreads();
        if (kt < 11) stage(kt + 1);
        #pragma unroll
        for (int i = 0; i < 4; ++i)
            #pragma unroll
            for (int j = 0; j < 4; ++j) {
                acc[i][j] = __builtin_amdgcn_mfma_f32_16x16x32_bf16(fAh[i], fBh[j], acc[i][j], 0, 0, 0);
                acc[i][j] = __builtin_amdgcn_mfma_f32_16x16x32_bf16(fAh[i], fBl[j], acc[i][j], 0, 0, 0);
                acc[i][j] = __builtin_amdgcn_mfma_f32_16x16x32_bf16(fAl[i], fBh[j], acc[i][j], 0, 0, 0);
            }
    }

    // epilogue: C/D layout col = lane&15, row = (lane>>4)*4 + reg.
    // Row m = b*96 + t of the [B][T] flattening -> store at [t][b].
    #pragma unroll
    for (int j = 0; j < 4; ++j) {
        const int gcol = gn0 + wc*64 + j*16 + lr;
        if (gcol < G3_) {
            const float bv = bias[gcol];
            #pragma unroll
            for (int i = 0; i < 4; ++i) {
                const int grow = gm0 + wr*64 + i*16 + lk*4;
                #pragma unroll
                for (int q = 0; q < 4; ++q) {
                    const int m = grow + q;
                    const int bq = m / T_, tq = m - bq*T_;
                    C[((size_t)tq*B_ + bq)*G3_ + gcol] = acc[i][j][q] + bv;
                }
            }
        }
    }
}

// ---------------------------------------------------------------------------
// K2 v17: PERSISTENT MFMA GRU (byte-identical to round 12's 325 us kernel).
// v13 protocol + bg-major placement (a bg's 8 WGs spread one-per-XCD) +
// own-slice LDS bypass + xprojT gate window. Dense h2 [t][bg][u][r],
// per-word sentinel polling with exec-masked straggler retry, LDS barriers.
// ---------------------------------------------------------------------------
__global__ __launch_bounds__(512, 2) void k_gru_all(const float* __restrict__ xprojT,
                                                    const unsigned short* __restrict__ Wq2,
                                                    const float* __restrict__ bh,
                                                    unsigned int* __restrict__ h2) {
    __shared__ unsigned short sAh[2][6144];     // [buf][k-chunk48*row16*e8], 24576 B
    __shared__ unsigned short sAl[2][6144];     // 24576 B
    __shared__ float part2[4][144][9];          // [wk][col][row+pad], 20736 B
    const int tid = threadIdx.x;
    const int us  = blockIdx.x & 7;             // bg-major (v13 placement)
    const int bg  = blockIdx.x >> 3;            // consecutive blocks = one bg
    const int b0  = bg * ROWS;
    const int w   = tid >> 6;                   // wave 0..7
    const int l   = tid & 63;
    const int wk  = w >> 1;                     // K quarter (3 k-tiles)
    const int wn  = w & 1;                      // N half: tiles wn*4..wn*4+4
    const int nt0 = wn * 4;

    // zero-init LDS: A pad rows stay 0 forever; part2 zero for t=0
    for (int s = tid; s < 6144; s += 512) {
        sAh[0][s] = 0; sAh[1][s] = 0; sAl[0][s] = 0; sAl[1][s] = 0;
    }
    for (int s = tid; s < 4*144*9; s += 512) (&part2[0][0][0])[s] = 0.f;

    // preload static B fragments: 5 tiles x 3 k-tiles x 2 planes = 120 VGPR
    bhalf8 bB[5][3][2];
    #pragma unroll
    for (int ti = 0; ti < 5; ++ti)
        #pragma unroll
        for (int kti = 0; kti < 3; ++kti)
            #pragma unroll
            for (int p = 0; p < 2; ++p)
                bB[ti][kti][p] = *reinterpret_cast<const bhalf8*>(
                    Wq2 + ((((size_t)(us*9 + nt0 + ti)*12 + (wk*3 + kti))*2 + p)*64 + l)*8);

    // gate-phase constants (one item per thread, tid < 368)
    const bool gact = tid < ROWS*NU;
    const int u1 = tid % NU, r1 = tid / NU;
    const int ug1 = us*NU + u1;
    const int ga  = ((ug1 >> 3)*16 + r1)*8 + (ug1 & 7);   // own-slice LDS slot
    float bh1r = 0.f, bh1z = 0.f, bh1n = 0.f;
    if (gact) { bh1r = bh[ug1]; bh1z = bh[H_+ug1]; bh1n = bh[2*H_+ug1]; }

    // staging geometry: wave w stages slice w = contiguous 184 u64 at u64
    // offset 184*w in the bg's 2944-word step block (skipped when w == us).
    int aoff2[3]; bool sact[3];
    #pragma unroll
    for (int ii = 0; ii < 3; ++ii) {
        const int pi = l + ii*64;
        sact[ii] = pi < 184;
        const int pc = sact[ii] ? pi : 0;
        const int u = NU*w + (pc >> 2), r2 = pc & 3;
        aoff2[ii] = ((u >> 3)*16 + 2*r2)*8 + (u & 7);
    }

    // per-lane A-frag LDS byte offset within a k-tile block (1024 B / k-tile)
    const int aoffb = (l >> 4)*256 + (l & 15)*16;

    __syncthreads();

    for (int t = 0; t < T_; ++t) {
        const int rb = (t - 1) & 1;             // buffer holding h(t-1)
        const int wb = t & 1;                   // buffer receiving h(t)
        unsigned int* hout = h2 + ((size_t)t*32 + bg)*2944;   // [u][r] dense

        // prefetch gate operands from xprojT (contiguous window; hides
        // under poll/MFMA)
        float xg10 = 0.f, xg11 = 0.f, xg12 = 0.f;
        if (gact) {
            const float* xp = xprojT + ((size_t)t*B_ + b0 + r1)*G3_;
            xg10 = xp[ug1]; xg11 = xp[H_+ug1]; xg12 = xp[2*H_+ug1];
        }

        if (t > 0) {
            if (w != us) {
                // poll-load slice w of h(t-1): data words ARE the flags.
                const unsigned long long* hin64 =
                    reinterpret_cast<const unsigned long long*>(
                        h2 + ((size_t)(t - 1)*32 + bg)*2944) + 184*w;
                unsigned long long v[3];
                bool need[3];
                #pragma unroll
                for (int ii = 0; ii < 3; ++ii) {
                    need[ii] = sact[ii];
                    v[ii] = 0ull;
                    if (need[ii]) v[ii] = bload_u2(hin64 + l + ii*64);
                }
                for (;;) {
                    unsigned bad = 0u;
                    #pragma unroll
                    for (int ii = 0; ii < 3; ++ii) {
                        if (need[ii]) {
                            const bool inv = ((unsigned)v[ii] == SENT) ||
                                             ((unsigned)(v[ii] >> 32) == SENT);
                            need[ii] = inv;
                            if (inv) bad = 1u;
                        }
                    }
                    if (!__any(bad != 0u)) break;
                    #pragma unroll
                    for (int ii = 0; ii < 3; ++ii)
                        if (need[ii]) v[ii] = bload_u2(hin64 + l + ii*64);
                }
                #pragma unroll
                for (int ii = 0; ii < 3; ++ii) {
                    if (sact[ii]) {
                        const unsigned int v0 = (unsigned int)v[ii];
                        const unsigned int v1 = (unsigned int)(v[ii] >> 32);
                        const int a = aoff2[ii];
                        sAh[rb][a]     = (unsigned short)(v0 & 0xffffu);
                        sAl[rb][a]     = (unsigned short)(v0 >> 16);
                        sAh[rb][a + 8] = (unsigned short)(v1 & 0xffffu);
                        sAl[rb][a + 8] = (unsigned short)(v1 >> 16);
                    }
                }
            }
            // own slice (w == us) already sits in sA[rb], written by the
            // gates of step t-1 — no global round trip.
            barrier_lds();
            // MFMA: 3 k-tiles x 5 n-tiles x 3 split terms = 45 MFMAs/wave
            f32x4 acc[5];
            #pragma unroll
            for (int ti = 0; ti < 5; ++ti) acc[ti] = f32x4{0.f,0.f,0.f,0.f};
            #pragma unroll
            for (int kti = 0; kti < 3; ++kti) {
                const int kt = wk*3 + kti;
                const bhalf8 fh = *reinterpret_cast<const bhalf8*>(
                    (const char*)sAh[rb] + kt*1024 + aoffb);
                const bhalf8 fl = *reinterpret_cast<const bhalf8*>(
                    (const char*)sAl[rb] + kt*1024 + aoffb);
                #pragma unroll
                for (int ti = 0; ti < 5; ++ti) {
                    acc[ti] = __builtin_amdgcn_mfma_f32_16x16x32_bf16(fh, bB[ti][kti][0], acc[ti], 0, 0, 0);
                    acc[ti] = __builtin_amdgcn_mfma_f32_16x16x32_bf16(fh, bB[ti][kti][1], acc[ti], 0, 0, 0);
                    acc[ti] = __builtin_amdgcn_mfma_f32_16x16x32_bf16(fl, bB[ti][kti][0], acc[ti], 0, 0, 0);
                }
            }
            // C frags -> per-wk partials (padded, conflict-free).
            // C layout: col=lane&15, row=(lane>>4)*4+reg; rows 0..7 in lanes 0..31.
            if (l < 32) {
                #pragma unroll
                for (int ti = 0; ti < 5; ++ti) {
                    const int col = (nt0 + ti)*16 + (l & 15);
                    float* pp = &part2[wk][col][(l >> 4)*4];
                    pp[0] = acc[ti][0]; pp[1] = acc[ti][1];
                    pp[2] = acc[ti][2]; pp[3] = acc[ti][3];
                }
            }
        }
        barrier_lds();

        // fused gates: one (unit,row) per thread
        if (gact) {
            float s0 = 0.f, s1 = 0.f, s2 = 0.f;
            #pragma unroll
            for (int q2 = 0; q2 < 4; ++q2) {
                s0 += part2[q2][u1][r1];
                s1 += part2[q2][NU + u1][r1];
                s2 += part2[q2][2*NU + u1][r1];
            }
            const float rg = 1.f/(1.f + expf(-(xg10 + s0 + bh1r)));
            const float zg = 1.f/(1.f + expf(-(xg11 + s1 + bh1z)));
            const float ng = tanhf(xg12 + rg*(s2 + bh1n));
            float hp = 0.f;
            if (t > 0) hp = bf2f(sAh[rb][ga]) + bf2f(sAl[rb][ga]);
            const float hn = (1.f - zg)*ng + zg*hp;
            const unsigned short hi = f2bf(hn);
            const unsigned short lo = f2bf(hn - bf2f(hi));
            sAh[wb][ga] = hi; sAl[wb][ga] = lo;   // own slice, next step's A
            bstore_u(hout + ug1*8 + r1, (unsigned)hi | ((unsigned)lo << 16));
        }
        // LDS WAR (gates' part2/sA reads precede next step's writes);
        // h stores intentionally NOT drained — words self-validate.
        barrier_lds();
    }
}

// ---------------------------------------------------------------------------
// K3: heads on temporal2 [t][bg][u][r] packed bf16 hi|lo; h = hi + lo.
// Wc/Wf read DIRECTLY (thread-uniform addresses -> scalar broadcast loads;
// 32 KB, cache-resident) — prep_wcat kernel deleted.
// ---------------------------------------------------------------------------
__global__ __launch_bounds__(256) void k_heads2(const unsigned int* __restrict__ temporal2,
                                                const float* __restrict__ Wc,
                                                const float* __restrict__ Wf,
                                                const float* __restrict__ bc,
                                                const float* __restrict__ bf,
                                                float* __restrict__ cs,
                                                float* __restrict__ fine_out) {
    const int t = blockIdx.x;       // 0..95
    const int b = threadIdx.x;      // 0..255
    const unsigned int* tb = temporal2 + (size_t)t*HB_ + (b >> 3)*2944 + (b & 7);
    float acc[31];
    #pragma unroll
    for (int c = 0; c < 31; ++c) acc[c] = 0.f;
    for (int u = 0; u < H_; ++u) {
        const unsigned int v = tb[(size_t)u*8];
        const float x = bf2f((unsigned short)(v & 0xffffu)) + bf2f((unsigned short)(v >> 16));
        acc[0] = fmaf(x, Wc[u], acc[0]);
        acc[1] = fmaf(x, Wc[H_ + u], acc[1]);
        #pragma unroll
        for (int c = 2; c < 31; ++c) acc[c] = fmaf(x, Wf[(c-2)*H_ + u], acc[c]);
    }
    const float l0 = acc[0] + bc[0], l1 = acc[1] + bc[1];
    const float m  = fmaxf(l0, l1);
    const float e0 = expf(l0 - m), e1 = expf(l1 - m);
    const float inv = 1.f/(e0 + e1);
    cs[((size_t)b*T_ + t)*2]     = e0*inv;
    cs[((size_t)b*T_ + t)*2 + 1] = e1*inv;
    #pragma unroll
    for (int c = 2; c < 31; ++c) {
        fine_out[((size_t)b*T_ + t)*NC_ + (c-2)] = 1.f/(1.f + expf(-(acc[c] + bf[c-2])));
    }
}

// ---------------------------------------------------------------------------
// K4: NMS + argmax
// ---------------------------------------------------------------------------
__global__ __launch_bounds__(256) void k_nms(const float* __restrict__ cs,
                                             float* __restrict__ out_dec,
                                             float* __restrict__ out_nms) {
    const int idx = blockIdx.x*256 + threadIdx.x;   // < 24576
    const int t = idx % T_;
    const float bg = cs[idx*2], s1 = cs[idx*2+1];
    float wmin = bg;
    #pragma unroll
    for (int dt = -2; dt <= 2; ++dt) {
        const int tt = t + dt;
        if (dt != 0 && tt >= 0 && tt < T_) wmin = fminf(wmin, cs[(idx + dt)*2]);
    }
    const bool keep = (bg <= wmin);
    out_dec[idx]     = (keep && (s1 > bg)) ? 1.f : 0.f;
    out_nms[idx*2]   = keep ? bg : 0.f;
    out_nms[idx*2+1] = keep ? s1 : 0.f;
}

// ---------------------------------------------------------------------------
extern "C" void kernel_launch(void* const* d_in, const int* in_sizes, int n_in,
                              void* d_out, int out_size, void* d_ws, size_t ws_size,
                              hipStream_t stream) {
    const float* features = (const float*)d_in[0];
    const float* Wi = (const float*)d_in[2];
    const float* Wh = (const float*)d_in[3];
    const float* bi = (const float*)d_in[4];
    const float* bh = (const float*)d_in[5];
    const float* Wc = (const float*)d_in[6];
    const float* bc = (const float*)d_in[7];
    const float* Wf = (const float*)d_in[8];
    const float* bf = (const float*)d_in[9];

    float* out = (float*)d_out;
    float* out_dec  = out;                 // (B,T)     24576
    float* out_nms  = out + BT_;           // (B,T,2)   49152
    float* out_fine = out + BT_ + 2*BT_;   // (B,T,29)  712704

    // workspace: xprojT f32 [t][b][g3] | Wq2 u16 frags | temporal2 u32
    float* xprojT = (float*)d_ws;
    unsigned short* Wq2 = (unsigned short*)(xprojT + (size_t)BT_*G3_);
    unsigned int* temporal2 = (unsigned int*)((char*)Wq2 + (size_t)WQ2_U16*2);
    float* cs = xprojT + 12288;            // xprojT dead after GRU

    // phase-1 overlays (dead once consumers below run, stream-ordered):
    //   Bh/Bl (847,872 u16) fits inside Wq2 region (884,736 u16)
    //   Ah/Al (36,175,872 B) == temporal2 region exactly
    unsigned short* Bh16 = (unsigned short*)Wq2;
    unsigned short* Bl16 = Bh16 + (size_t)WQCOLS*F_;
    unsigned short* Ah16 = (unsigned short*)temporal2;
    unsigned short* Al16 = Ah16 + (size_t)BT_*F_;

    k_split_ab<<<10488, 256, 0, stream>>>(features, Wi, Ah16, Al16, Bh16, Bl16);
    k_xproj_mfma<<<dim3(9, 192), 256, 0, stream>>>(Ah16, Al16, Bh16, Bl16, bi, xprojT);
    k_prep_fill<<<9264, 256, 0, stream>>>(Wh, Wq2, temporal2);  // overwrites overlays (dead)
    k_gru_all<<<256, 512, 0, stream>>>(xprojT, Wq2, bh, temporal2);
    k_heads2<<<96, 256, 0, stream>>>(temporal2, Wc, Wf, bc, bf, cs, out_fine);
    k_nms<<<96, 256, 0, stream>>>(cs, out_dec, out_nms);
}

// Round 14
// 597.538 us; speedup vs baseline: 1.0382x; 1.0382x over previous
//
#include <hip/hip_runtime.h>
#include <hip/hip_bf16.h>

// Problem constants
#define B_ 256
#define T_ 96
#define F_ 368
#define H_ 368
#define G3_ 1104          // 3*H
#define NC_ 29            // fine classes
#define BT_ (B_*T_)       // 24576
#define HB_ (H_*B_)       // 94208, one time-slice of h2 [bg][u][r]

// GRU geometry (v17 = v13 bg-major placement + own-slice bypass + xprojT)
#define NSL 8             // unit slices
#define NU 46             // units per slice (8*46 = 368)
#define NCOL 138          // cols per slice = 3*NU
#define ROWS 8            // batch rows per group
#define WQCOLS 1152       // legacy, overlay sizing

// Wq2 frag store: [us 8][nt 9][kt 12][plane 2][lane 64][e 8] u16 = 1,769,472 B
#define WQ2_U16 (8*9*12*2*64*8)

// h-word sentinel: hi half 0x7FC0 = bf16 NaN; finite h can never produce it,
// so a non-sentinel full-word read proves the producer's store landed.
#define SENT 0x7FC07FC0u

typedef __attribute__((ext_vector_type(8))) short bhalf8;   // 8 bf16 = 4 VGPR
typedef __attribute__((ext_vector_type(4))) float f32x4;

// ---- bf16 split helpers (bit-level RNE, no header dependence) -------------
__device__ __forceinline__ unsigned short f2bf(float x) {
    unsigned u = __float_as_uint(x);
    u += 0x7fffu + ((u >> 16) & 1u);
    return (unsigned short)(u >> 16);
}
__device__ __forceinline__ float bf2f(unsigned short b) {
    return __uint_as_float(((unsigned)b) << 16);
}

// async global->LDS, 16B per lane; lds base must be wave-uniform
__device__ __forceinline__ void gll16(const void* g, void* l) {
    __builtin_amdgcn_global_load_lds(
        (const __attribute__((address_space(1))) void*)g,
        (__attribute__((address_space(3))) void*)l, 16, 0, 0);
}

// ---- fence-free cross-XCD exchange primitives ----------------------------
__device__ __forceinline__ void bstore_u(unsigned int* p, unsigned int v) {
    __hip_atomic_store(p, v, __ATOMIC_RELAXED, __HIP_MEMORY_SCOPE_AGENT);
}
__device__ __forceinline__ unsigned long long bload_u2(const unsigned long long* p) {
    return __hip_atomic_load(p, __ATOMIC_RELAXED, __HIP_MEMORY_SCOPE_AGENT);
}

// LDS-only barrier: orders ds ops across the WG WITHOUT draining vmcnt, so
// in-flight agent-scope h stores keep flying across step boundaries.
__device__ __forceinline__ void barrier_lds() {
    asm volatile("s_waitcnt lgkmcnt(0)\ns_barrier" ::: "memory");
}

// ---------------------------------------------------------------------------
// K0: pack Wh (1104x368) into bf16 hi/lo B-fragments Wq2 (v13 layout).
// ---------------------------------------------------------------------------
__global__ __launch_bounds__(256) void k_prep_wq2(const float* __restrict__ Wh,
                                                  unsigned short* __restrict__ Wq2) {
    const int idx = blockIdx.x*256 + threadIdx.x;   // < 110592 (432 blocks exact)
    const int l = idx & 63;
    const int p = (idx >> 6) & 1;
    int q = idx >> 7;
    const int kt = q % 12; q /= 12;
    const int nt = q % 9;
    const int us = q / 9;
    const int col = nt*16 + (l & 15);
    const int k0 = kt*32 + (l >> 4)*8;              // multiple of 8; 368%8==0
    float v[8];
    #pragma unroll
    for (int e = 0; e < 8; ++e) v[e] = 0.f;
    if (col < NCOL && k0 < H_) {
        const int g = col / NU, uu = col - g*NU;
        const int grow = g*H_ + us*NU + uu;         // < 1104
        const float4 f0 = *reinterpret_cast<const float4*>(Wh + (size_t)grow*H_ + k0);
        const float4 f1 = *reinterpret_cast<const float4*>(Wh + (size_t)grow*H_ + k0 + 4);
        v[0]=f0.x; v[1]=f0.y; v[2]=f0.z; v[3]=f0.w;
        v[4]=f1.x; v[5]=f1.y; v[6]=f1.z; v[7]=f1.w;
    }
    unsigned int o[4];
    #pragma unroll
    for (int e = 0; e < 4; ++e) {
        const unsigned short h0 = f2bf(v[2*e]), h1 = f2bf(v[2*e+1]);
        const unsigned short w0 = p ? f2bf(v[2*e]   - bf2f(h0)) : h0;
        const unsigned short w1 = p ? f2bf(v[2*e+1] - bf2f(h1)) : h1;
        o[e] = (unsigned)w0 | ((unsigned)w1 << 16);
    }
    uint4* dst = reinterpret_cast<uint4*>(Wq2 + (size_t)idx*8);
    *dst = make_uint4(o[0], o[1], o[2], o[3]);
}

// ---------------------------------------------------------------------------
// K0b: pack head weights Wcat[u][32]
// ---------------------------------------------------------------------------
__global__ __launch_bounds__(256) void k_prep_wcat(const float* __restrict__ Wc,
                                                   const float* __restrict__ Wf,
                                                   float* __restrict__ Wcat) {
    const int idx = blockIdx.x*256 + threadIdx.x;   // < 368*32 = 11776
    const int u = idx >> 5, c = idx & 31;
    float v = 0.f;
    if (c < 2) v = Wc[c*H_ + u];
    else if (c < 31) v = Wf[(c-2)*H_ + u];
    Wcat[idx] = v;
}

// ---------------------------------------------------------------------------
// K0f: fill the h-exchange buffer with the sentinel (re-poison each launch).
// 8832*256*4 u32 == 96*32*368*8 exactly.
// ---------------------------------------------------------------------------
__global__ __launch_bounds__(256) void k_fill_sent(unsigned int* __restrict__ p) {
    const int idx = blockIdx.x*256 + threadIdx.x;
    reinterpret_cast<uint4*>(p)[idx] = make_uint4(SENT, SENT, SENT, SENT);
}

// ---------------------------------------------------------------------------
// K0d: split features into hi/lo bf16 planes (Markidis split).
// ---------------------------------------------------------------------------
__global__ __launch_bounds__(256) void k_split_a(const float* __restrict__ src,
                                                 unsigned short* __restrict__ Ah,
                                                 unsigned short* __restrict__ Al) {
    const int idx = blockIdx.x*256 + threadIdx.x;
    const float4 v = reinterpret_cast<const float4*>(src)[idx];
    ushort4 h, lo;
    h.x = f2bf(v.x); lo.x = f2bf(v.x - bf2f(h.x));
    h.y = f2bf(v.y); lo.y = f2bf(v.y - bf2f(h.y));
    h.z = f2bf(v.z); lo.z = f2bf(v.z - bf2f(h.z));
    h.w = f2bf(v.w); lo.w = f2bf(v.w - bf2f(h.w));
    reinterpret_cast<ushort4*>(Ah)[idx] = h;
    reinterpret_cast<ushort4*>(Al)[idx] = lo;
}

// K0e: split Wi (1104x368) into hi/lo bf16, zero-padded to 1152 N-rows.
__global__ __launch_bounds__(256) void k_split_b(const float* __restrict__ Wi,
                                                 unsigned short* __restrict__ Bh,
                                                 unsigned short* __restrict__ Bl) {
    const int idx = blockIdx.x*256 + threadIdx.x;
    const float x = (idx < G3_*F_) ? Wi[idx] : 0.f;
    const unsigned short h = f2bf(x);
    Bh[idx] = h;
    Bl[idx] = f2bf(x - bf2f(h));
}

// ---------------------------------------------------------------------------
// K1: xproj GEMM via split-bf16 MFMA; TRANSPOSED epilogue stores
// xprojT[t][b][g3] (compiled+passed rounds 8/10/11/12) so the GRU's per-step
// gate loads hit one contiguous 1.1 MB window (L2/L3-resident).
// ---------------------------------------------------------------------------
__global__ __launch_bounds__(256) void k_xproj_mfma(
        const unsigned short* __restrict__ Ah, const unsigned short* __restrict__ Al,
        const unsigned short* __restrict__ Bh, const unsigned short* __restrict__ Bl,
        const float* __restrict__ bias, float* __restrict__ C)
{
    __shared__ unsigned short sAh[128*32], sAl[128*32], sBh[128*32], sBl[128*32];
    const int tid = threadIdx.x;
    const int w   = tid >> 6, l = tid & 63;
    const int gm0 = blockIdx.y * 128, gn0 = blockIdx.x * 128;

    const int srow = tid >> 2;                       // 0..63
    const int cg   = (tid & 3) ^ ((tid >> 3) & 3);   // source k-chunk (0..3)
    const size_t aoff0 = (size_t)(gm0 + srow)      * F_ + cg * 8;
    const size_t aoff1 = (size_t)(gm0 + srow + 64) * F_ + cg * 8;
    const size_t boff0 = (size_t)(gn0 + srow)      * F_ + cg * 8;
    const size_t boff1 = (size_t)(gn0 + srow + 64) * F_ + cg * 8;
    const int lb0 = w * 1024, lb1 = 4096 + w * 1024; // wave-uniform LDS bases

    const int lr = l & 15, lk = l >> 4;
    const int cswz = (lk ^ ((lr >> 1) & 3)) * 16;
    const int wr = w >> 1, wc = w & 1;
    int offA[4], offB[4];
    #pragma unroll
    for (int f = 0; f < 4; ++f) {
        offA[f] = (wr*64 + f*16 + lr) * 64 + cswz;
        offB[f] = (wc*64 + f*16 + lr) * 64 + cswz;
    }

    f32x4 acc[4][4];
    #pragma unroll
    for (int i = 0; i < 4; ++i)
        #pragma unroll
        for (int j = 0; j < 4; ++j) acc[i][j] = f32x4{0.f,0.f,0.f,0.f};

    auto stage = [&](int kt) {
        const size_t ko = (size_t)kt * 32;
        gll16(Ah + aoff0 + ko, (char*)sAh + lb0);
        gll16(Ah + aoff1 + ko, (char*)sAh + lb1);
        gll16(Al + aoff0 + ko, (char*)sAl + lb0);
        gll16(Al + aoff1 + ko, (char*)sAl + lb1);
        gll16(Bh + boff0 + ko, (char*)sBh + lb0);
        gll16(Bh + boff1 + ko, (char*)sBh + lb1);
        gll16(Bl + boff0 + ko, (char*)sBl + lb0);
        gll16(Bl + boff1 + ko, (char*)sBl + lb1);
    };

    stage(0);
    for (int kt = 0; kt < 12; ++kt) {
        __syncthreads();
        if (kt == 11) {
            if (cg >= 2) {
                const f32x4 z = f32x4{0.f,0.f,0.f,0.f};
                *reinterpret_cast<f32x4*>((char*)sAh + tid*16)        = z;
                *reinterpret_cast<f32x4*>((char*)sAh + tid*16 + 4096) = z;
                *reinterpret_cast<f32x4*>((char*)sAl + tid*16)        = z;
                *reinterpret_cast<f32x4*>((char*)sAl + tid*16 + 4096) = z;
                *reinterpret_cast<f32x4*>((char*)sBh + tid*16)        = z;
                *reinterpret_cast<f32x4*>((char*)sBh + tid*16 + 4096) = z;
                *reinterpret_cast<f32x4*>((char*)sBl + tid*16)        = z;
                *reinterpret_cast<f32x4*>((char*)sBl + tid*16 + 4096) = z;
            }
            __syncthreads();
        }
        bhalf8 fAh[4], fAl[4], fBh[4], fBl[4];
        #pragma unroll
        for (int f = 0; f < 4; ++f) {
            fAh[f] = *reinterpret_cast<const bhalf8*>((const char*)sAh + offA[f]);
            fAl[f] = *reinterpret_cast<const bhalf8*>((const char*)sAl + offA[f]);
            fBh[f] = *reinterpret_cast<const bhalf8*>((const char*)sBh + offB[f]);
            fBl[f] = *reinterpret_cast<const bhalf8*>((const char*)sBl + offB[f]);
        }
        __syncthreads();
        if (kt < 11) stage(kt + 1);
        #pragma unroll
        for (int i = 0; i < 4; ++i)
            #pragma unroll
            for (int j = 0; j < 4; ++j) {
                acc[i][j] = __builtin_amdgcn_mfma_f32_16x16x32_bf16(fAh[i], fBh[j], acc[i][j], 0, 0, 0);
                acc[i][j] = __builtin_amdgcn_mfma_f32_16x16x32_bf16(fAh[i], fBl[j], acc[i][j], 0, 0, 0);
                acc[i][j] = __builtin_amdgcn_mfma_f32_16x16x32_bf16(fAl[i], fBh[j], acc[i][j], 0, 0, 0);
            }
    }

    // epilogue: C/D layout col = lane&15, row = (lane>>4)*4 + reg.
    // Row m = b*96 + t of the [B][T] flattening -> store at [t][b].
    #pragma unroll
    for (int j = 0; j < 4; ++j) {
        const int gcol = gn0 + wc*64 + j*16 + lr;
        if (gcol < G3_) {
            const float bv = bias[gcol];
            #pragma unroll
            for (int i = 0; i < 4; ++i) {
                const int grow = gm0 + wr*64 + i*16 + lk*4;
                #pragma unroll
                for (int q = 0; q < 4; ++q) {
                    const int m = grow + q;
                    const int bq = m / T_, tq = m - bq*T_;
                    C[((size_t)tq*B_ + bq)*G3_ + gcol] = acc[i][j][q] + bv;
                }
            }
        }
    }
}

// ---------------------------------------------------------------------------
// K2 v17: PERSISTENT MFMA GRU = v13 protocol + bg-major placement (spreads a
// bg's 8 WGs one-per-XCD — 8 L3 ports in parallel; us-major concentration
// measured −1.3 us/step worse) + own-slice LDS bypass + xprojT gate window.
// Exchange: dense h2 [t][bg][u][r], per-word sentinel polling with
// exec-masked straggler retry, LDS-only barriers.
// ---------------------------------------------------------------------------
__global__ __launch_bounds__(512, 2) void k_gru_all(const float* __restrict__ xprojT,
                                                    const unsigned short* __restrict__ Wq2,
                                                    const float* __restrict__ bh,
                                                    unsigned int* __restrict__ h2) {
    __shared__ unsigned short sAh[2][6144];     // [buf][k-chunk48*row16*e8], 24576 B
    __shared__ unsigned short sAl[2][6144];     // 24576 B
    __shared__ float part2[4][144][9];          // [wk][col][row+pad], 20736 B
    const int tid = threadIdx.x;
    const int us  = blockIdx.x & 7;             // bg-major (v13 placement)
    const int bg  = blockIdx.x >> 3;            // consecutive blocks = one bg
    const int b0  = bg * ROWS;
    const int w   = tid >> 6;                   // wave 0..7
    const int l   = tid & 63;
    const int wk  = w >> 1;                     // K quarter (3 k-tiles)
    const int wn  = w & 1;                      // N half: tiles wn*4..wn*4+4
    const int nt0 = wn * 4;

    // zero-init LDS: A pad rows stay 0 forever; part2 zero for t=0
    for (int s = tid; s < 6144; s += 512) {
        sAh[0][s] = 0; sAh[1][s] = 0; sAl[0][s] = 0; sAl[1][s] = 0;
    }
    for (int s = tid; s < 4*144*9; s += 512) (&part2[0][0][0])[s] = 0.f;

    // preload static B fragments: 5 tiles x 3 k-tiles x 2 planes = 120 VGPR
    bhalf8 bB[5][3][2];
    #pragma unroll
    for (int ti = 0; ti < 5; ++ti)
        #pragma unroll
        for (int kti = 0; kti < 3; ++kti)
            #pragma unroll
            for (int p = 0; p < 2; ++p)
                bB[ti][kti][p] = *reinterpret_cast<const bhalf8*>(
                    Wq2 + ((((size_t)(us*9 + nt0 + ti)*12 + (wk*3 + kti))*2 + p)*64 + l)*8);

    // gate-phase constants (one item per thread, tid < 368)
    const bool gact = tid < ROWS*NU;
    const int u1 = tid % NU, r1 = tid / NU;
    const int ug1 = us*NU + u1;
    const int ga  = ((ug1 >> 3)*16 + r1)*8 + (ug1 & 7);   // own-slice LDS slot
    float bh1r = 0.f, bh1z = 0.f, bh1n = 0.f;
    if (gact) { bh1r = bh[ug1]; bh1z = bh[H_+ug1]; bh1n = bh[2*H_+ug1]; }

    // staging geometry: wave w stages slice w = contiguous 184 u64 at u64
    // offset 184*w in the bg's 2944-word step block (skipped when w == us).
    int aoff2[3]; bool sact[3];
    #pragma unroll
    for (int ii = 0; ii < 3; ++ii) {
        const int pi = l + ii*64;
        sact[ii] = pi < 184;
        const int pc = sact[ii] ? pi : 0;
        const int u = NU*w + (pc >> 2), r2 = pc & 3;
        aoff2[ii] = ((u >> 3)*16 + 2*r2)*8 + (u & 7);
    }

    // per-lane A-frag LDS byte offset within a k-tile block (1024 B / k-tile)
    const int aoffb = (l >> 4)*256 + (l & 15)*16;

    __syncthreads();

    for (int t = 0; t < T_; ++t) {
        const int rb = (t - 1) & 1;             // buffer holding h(t-1)
        const int wb = t & 1;                   // buffer receiving h(t)
        unsigned int* hout = h2 + ((size_t)t*32 + bg)*2944;   // [u][r] dense

        // prefetch gate operands from xprojT (contiguous window; hides
        // under poll/MFMA)
        float xg10 = 0.f, xg11 = 0.f, xg12 = 0.f;
        if (gact) {
            const float* xp = xprojT + ((size_t)t*B_ + b0 + r1)*G3_;
            xg10 = xp[ug1]; xg11 = xp[H_+ug1]; xg12 = xp[2*H_+ug1];
        }

        if (t > 0) {
            if (w != us) {
                // poll-load slice w of h(t-1): data words ARE the flags.
                // Initial coalesced read of all 184 u64, then retry ONLY
                // stragglers (exec-masked) until no lane sees the sentinel.
                const unsigned long long* hin64 =
                    reinterpret_cast<const unsigned long long*>(
                        h2 + ((size_t)(t - 1)*32 + bg)*2944) + 184*w;
                unsigned long long v[3];
                bool need[3];
                #pragma unroll
                for (int ii = 0; ii < 3; ++ii) {
                    need[ii] = sact[ii];
                    v[ii] = 0ull;
                    if (need[ii]) v[ii] = bload_u2(hin64 + l + ii*64);
                }
                for (;;) {
                    unsigned bad = 0u;
                    #pragma unroll
                    for (int ii = 0; ii < 3; ++ii) {
                        if (need[ii]) {
                            const bool inv = ((unsigned)v[ii] == SENT) ||
                                             ((unsigned)(v[ii] >> 32) == SENT);
                            need[ii] = inv;
                            if (inv) bad = 1u;
                        }
                    }
                    if (!__any(bad != 0u)) break;
                    #pragma unroll
                    for (int ii = 0; ii < 3; ++ii)
                        if (need[ii]) v[ii] = bload_u2(hin64 + l + ii*64);
                }
                #pragma unroll
                for (int ii = 0; ii < 3; ++ii) {
                    if (sact[ii]) {
                        const unsigned int v0 = (unsigned int)v[ii];
                        const unsigned int v1 = (unsigned int)(v[ii] >> 32);
                        const int a = aoff2[ii];
                        sAh[rb][a]     = (unsigned short)(v0 & 0xffffu);
                        sAl[rb][a]     = (unsigned short)(v0 >> 16);
                        sAh[rb][a + 8] = (unsigned short)(v1 & 0xffffu);
                        sAl[rb][a + 8] = (unsigned short)(v1 >> 16);
                    }
                }
            }
            // own slice (w == us) already sits in sA[rb], written by the
            // gates of step t-1 — no global round trip.
            barrier_lds();
            // MFMA: 3 k-tiles x 5 n-tiles x 3 split terms = 45 MFMAs/wave
            f32x4 acc[5];
            #pragma unroll
            for (int ti = 0; ti < 5; ++ti) acc[ti] = f32x4{0.f,0.f,0.f,0.f};
            #pragma unroll
            for (int kti = 0; kti < 3; ++kti) {
                const int kt = wk*3 + kti;
                const bhalf8 fh = *reinterpret_cast<const bhalf8*>(
                    (const char*)sAh[rb] + kt*1024 + aoffb);
                const bhalf8 fl = *reinterpret_cast<const bhalf8*>(
                    (const char*)sAl[rb] + kt*1024 + aoffb);
                #pragma unroll
                for (int ti = 0; ti < 5; ++ti) {
                    acc[ti] = __builtin_amdgcn_mfma_f32_16x16x32_bf16(fh, bB[ti][kti][0], acc[ti], 0, 0, 0);
                    acc[ti] = __builtin_amdgcn_mfma_f32_16x16x32_bf16(fh, bB[ti][kti][1], acc[ti], 0, 0, 0);
                    acc[ti] = __builtin_amdgcn_mfma_f32_16x16x32_bf16(fl, bB[ti][kti][0], acc[ti], 0, 0, 0);
                }
            }
            // C frags -> per-wk partials (padded, conflict-free).
            // C layout: col=lane&15, row=(lane>>4)*4+reg; rows 0..7 in lanes 0..31.
            if (l < 32) {
                #pragma unroll
                for (int ti = 0; ti < 5; ++ti) {
                    const int col = (nt0 + ti)*16 + (l & 15);
                    float* pp = &part2[wk][col][(l >> 4)*4];
                    pp[0] = acc[ti][0]; pp[1] = acc[ti][1];
                    pp[2] = acc[ti][2]; pp[3] = acc[ti][3];
                }
            }
        }
        barrier_lds();

        // fused gates: one (unit,row) per thread
        if (gact) {
            float s0 = 0.f, s1 = 0.f, s2 = 0.f;
            #pragma unroll
            for (int q2 = 0; q2 < 4; ++q2) {
                s0 += part2[q2][u1][r1];
                s1 += part2[q2][NU + u1][r1];
                s2 += part2[q2][2*NU + u1][r1];
            }
            const float rg = 1.f/(1.f + expf(-(xg10 + s0 + bh1r)));
            const float zg = 1.f/(1.f + expf(-(xg11 + s1 + bh1z)));
            const float ng = tanhf(xg12 + rg*(s2 + bh1n));
            float hp = 0.f;
            if (t > 0) hp = bf2f(sAh[rb][ga]) + bf2f(sAl[rb][ga]);
            const float hn = (1.f - zg)*ng + zg*hp;
            const unsigned short hi = f2bf(hn);
            const unsigned short lo = f2bf(hn - bf2f(hi));
            sAh[wb][ga] = hi; sAl[wb][ga] = lo;   // own slice, next step's A
            bstore_u(hout + ug1*8 + r1, (unsigned)hi | ((unsigned)lo << 16));
        }
        // LDS WAR (gates' part2/sA reads precede next step's writes);
        // h stores intentionally NOT drained — words self-validate.
        barrier_lds();
    }
}

// ---------------------------------------------------------------------------
// K3: heads on temporal2 [t][bg][u][r] packed bf16 hi|lo; h = hi + lo.
// ---------------------------------------------------------------------------
__global__ __launch_bounds__(256) void k_heads2(const unsigned int* __restrict__ temporal2,
                                                const float* __restrict__ Wcat,
                                                const float* __restrict__ bc,
                                                const float* __restrict__ bf,
                                                float* __restrict__ cs,
                                                float* __restrict__ fine_out) {
    const int t = blockIdx.x;       // 0..95
    const int b = threadIdx.x;      // 0..255
    const unsigned int* tb = temporal2 + (size_t)t*HB_ + (b >> 3)*2944 + (b & 7);
    float acc[31];
    #pragma unroll
    for (int c = 0; c < 31; ++c) acc[c] = 0.f;
    for (int u = 0; u < H_; ++u) {
        const unsigned int v = tb[(size_t)u*8];
        const float x = bf2f((unsigned short)(v & 0xffffu)) + bf2f((unsigned short)(v >> 16));
        const float* wrow = Wcat + u*32;
        #pragma unroll
        for (int c = 0; c < 31; ++c) acc[c] = fmaf(x, wrow[c], acc[c]);
    }
    const float l0 = acc[0] + bc[0], l1 = acc[1] + bc[1];
    const float m  = fmaxf(l0, l1);
    const float e0 = expf(l0 - m), e1 = expf(l1 - m);
    const float inv = 1.f/(e0 + e1);
    cs[((size_t)b*T_ + t)*2]     = e0*inv;
    cs[((size_t)b*T_ + t)*2 + 1] = e1*inv;
    #pragma unroll
    for (int c = 2; c < 31; ++c) {
        fine_out[((size_t)b*T_ + t)*NC_ + (c-2)] = 1.f/(1.f + expf(-(acc[c] + bf[c-2])));
    }
}

// ---------------------------------------------------------------------------
// K4: NMS + argmax
// ---------------------------------------------------------------------------
__global__ __launch_bounds__(256) void k_nms(const float* __restrict__ cs,
                                             float* __restrict__ out_dec,
                                             float* __restrict__ out_nms) {
    const int idx = blockIdx.x*256 + threadIdx.x;   // < 24576
    const int t = idx % T_;
    const float bg = cs[idx*2], s1 = cs[idx*2+1];
    float wmin = bg;
    #pragma unroll
    for (int dt = -2; dt <= 2; ++dt) {
        const int tt = t + dt;
        if (dt != 0 && tt >= 0 && tt < T_) wmin = fminf(wmin, cs[(idx + dt)*2]);
    }
    const bool keep = (bg <= wmin);
    out_dec[idx]     = (keep && (s1 > bg)) ? 1.f : 0.f;
    out_nms[idx*2]   = keep ? bg : 0.f;
    out_nms[idx*2+1] = keep ? s1 : 0.f;
}

// ---------------------------------------------------------------------------
extern "C" void kernel_launch(void* const* d_in, const int* in_sizes, int n_in,
                              void* d_out, int out_size, void* d_ws, size_t ws_size,
                              hipStream_t stream) {
    const float* features = (const float*)d_in[0];
    const float* Wi = (const float*)d_in[2];
    const float* Wh = (const float*)d_in[3];
    const float* bi = (const float*)d_in[4];
    const float* bh = (const float*)d_in[5];
    const float* Wc = (const float*)d_in[6];
    const float* bc = (const float*)d_in[7];
    const float* Wf = (const float*)d_in[8];
    const float* bf = (const float*)d_in[9];

    float* out = (float*)d_out;
    float* out_dec  = out;                 // (B,T)     24576
    float* out_nms  = out + BT_;           // (B,T,2)   49152
    float* out_fine = out + BT_ + 2*BT_;   // (B,T,29)  712704

    // workspace: xprojT f32 [t][b][g3] | Wq2 u16 frags | temporal2 u32
    float* xprojT = (float*)d_ws;
    unsigned short* Wq2 = (unsigned short*)(xprojT + (size_t)BT_*G3_);
    unsigned int* temporal2 = (unsigned int*)((char*)Wq2 + (size_t)WQ2_U16*2);
    float* Wcat = xprojT;                  // xprojT dead after GRU
    float* cs   = xprojT + 12288;

    // phase-1 overlays (dead once consumers below run, stream-ordered):
    //   Bh/Bl (847,872 u16) fits inside Wq2 region (884,736 u16)
    //   Ah/Al (36,175,872 B) == temporal2 region exactly
    unsigned short* Bh16 = (unsigned short*)Wq2;
    unsigned short* Bl16 = Bh16 + (size_t)WQCOLS*F_;
    unsigned short* Ah16 = (unsigned short*)temporal2;
    unsigned short* Al16 = Ah16 + (size_t)BT_*F_;

    k_split_a<<<8832, 256, 0, stream>>>(features, Ah16, Al16);
    k_split_b<<<1656, 256, 0, stream>>>(Wi, Bh16, Bl16);
    k_xproj_mfma<<<dim3(9, 192), 256, 0, stream>>>(Ah16, Al16, Bh16, Bl16, bi, xprojT);
    k_prep_wq2<<<432, 256, 0, stream>>>(Wh, Wq2);        // overwrites Bh/Bl (dead)
    k_fill_sent<<<8832, 256, 0, stream>>>(temporal2);    // overwrites Ah/Al (dead); re-poison
    k_gru_all<<<256, 512, 0, stream>>>(xprojT, Wq2, bh, temporal2);
    k_prep_wcat<<<46, 256, 0, stream>>>(Wc, Wf, Wcat);
    k_heads2<<<96, 256, 0, stream>>>(temporal2, Wcat, bc, bf, cs, out_fine);
    k_nms<<<96, 256, 0, stream>>>(cs, out_dec, out_nms);
}